// Round 8
// baseline (142.772 us; speedup 1.0000x reference)
//
#include <hip/hip_runtime.h>

#define GAT_H 12
#define GAT_N 4096
#define GAT_F 64
#define LOG2E 1.4426950408889634f

// ---------------------------------------------------------------------------
// Algebra: with q = x_i*s_h + x_j*d_h,
//   exp(lrelu(q)) = B1(i,h) * max(E2^4, rho(i,h)) * E2
//   where E2  = exp2(0.2*log2e*d_h*x_j)   [192 KB table, L2-resident]
//         rho = exp2(-0.8*log2e*x_i*s_h)  [12 SGPRs/wave]
// B1 cancels in softmax. Inner loop per (i,j,h): shared sq/sq + max+mul+2fma.
//
// Round-6 lesson: the per-iter vmcnt(0)+ds_write+barrier drained the in-flight
// adj prefetch (~460 idle cyc/iter, VALUBusy 55%). Round-7: NO barriers in the
// loop. Register-only pipeline: table+x prefetched 1 iter deep (L2 ~300cyc <
// ~450cyc compute), adj 2 deep (HBM ~900cyc < 2 iters). Buffers are
// literal-indexed (macro) so nothing spills to scratch. 8 waves =
// (row-pair)x(head-group)x(j-half), 24 accumulators/wave (proven in R5).
// ---------------------------------------------------------------------------

__device__ float g_tab2[GAT_H * GAT_N];   // 192 KB: E2 table
__device__ float g_sd[2 * GAT_H + 1];     // s[12], d[12], mean(x)

__global__ __launch_bounds__(256) void gat_prep(const float* __restrict__ W,
                                                const float* __restrict__ a,
                                                const float* __restrict__ x) {
    const int b    = blockIdx.x;
    const int tid  = threadIdx.x;
    const int lane = tid & 63;
    const int wave = tid >> 6;

    if (b < GAT_H) {                       // s_h, d_h (wave 0 only)
        if (wave == 0) {
            const float wf = W[b * GAT_F + lane];
            float ps = wf * a[b * 2 * GAT_F + lane];
            float pd = wf * a[b * 2 * GAT_F + GAT_F + lane];
            #pragma unroll
            for (int off = 32; off > 0; off >>= 1) {
                ps += __shfl_xor(ps, off, 64);
                pd += __shfl_xor(pd, off, 64);
            }
            if (lane == 0) { g_sd[b] = ps; g_sd[GAT_H + b] = pd; }
        }
        return;
    }
    if (b == GAT_H) {                      // mean(x) fallback (wave 0 only)
        if (wave == 0) {
            float s = 0.0f;
            #pragma unroll
            for (int j = 0; j < GAT_N / 64; ++j) s += x[j * 64 + lane];
            #pragma unroll
            for (int off = 32; off > 0; off >>= 1) s += __shfl_xor(s, off, 64);
            if (lane == 0) g_sd[2 * GAT_H] = s * (1.0f / GAT_N);
        }
        return;
    }

    // Table blocks: bt in [0,48): h = bt>>2, 1024-wide j-chunk = bt&3.
    const int bt    = b - (GAT_H + 1);
    const int h     = bt >> 2;
    const int chunk = bt & 3;
    const float wf  = W[h * GAT_F + lane];
    float pd = wf * a[h * 2 * GAT_F + GAT_F + lane];
    #pragma unroll
    for (int off = 32; off > 0; off >>= 1) pd += __shfl_xor(pd, off, 64);
    const float dl5 = 0.2f * pd * LOG2E;
    #pragma unroll
    for (int k = 0; k < 4; ++k) {
        const int j = chunk * 1024 + k * 256 + tid;
        g_tab2[h * GAT_N + j] = __builtin_amdgcn_exp2f(dl5 * x[j]);
    }
}

// One pipelined iteration. B is a LITERAL (0/1) buffer index; IT the iter no.
// Order: consume adj/x -> reload adj (depth 2) -> issue table/x for IT+1
// -> main compute from tBuf[B]. No barriers; compiler emits counted vmcnt.
#define GAT_ITER(B, IT)                                                        \
    do {                                                                       \
        float am[2][4], axj[2][4];                                             \
        {                                                                      \
            const int*   ai0 = (const int*)&aBuf[B][0];                        \
            const int*   ai1 = (const int*)&aBuf[B][1];                        \
            const float* xp  = (const float*)&xBuf[B];                         \
            _Pragma("unroll")                                                  \
            for (int e = 0; e < 4; ++e) {                                      \
                am[0][e]  = (float)ai0[e];                                     \
                am[1][e]  = (float)ai1[e];                                     \
                axj[0][e] = am[0][e] * xp[e];                                  \
                axj[1][e] = am[1][e] * xp[e];                                  \
            }                                                                  \
        }                                                                      \
        const int i2_ = (((IT) < 6) ? (IT) + 2 : 7) * 64 + lane;               \
        aBuf[B][0] = a4p0[i2_];                                                \
        aBuf[B][1] = a4p1[i2_];                                                \
        const int i1_ = (((IT) < 7) ? (IT) + 1 : 7) * 64 + lane;               \
        _Pragma("unroll")                                                      \
        for (int hh = 0; hh < 6; ++hh)                                         \
            tBuf[(B) ^ 1][hh] = t4[hh * (GAT_N / 4) + i1_];                    \
        xBuf[(B) ^ 1] = x4[i1_];                                               \
        _Pragma("unroll")                                                      \
        for (int hh = 0; hh < 6; ++hh) {                                       \
            const float* e2 = (const float*)&tBuf[B][hh];                      \
            _Pragma("unroll")                                                  \
            for (int e = 0; e < 4; ++e) {                                      \
                const float w  = e2[e] * e2[e];                                \
                const float w4 = w * w;                /* E2^4 */              \
                const float p0 = fmaxf(w4, rho[0][hh]) * e2[e];                \
                const float p1 = fmaxf(w4, rho[1][hh]) * e2[e];                \
                den[0][hh] = fmaf(p0, am[0][e],  den[0][hh]);                  \
                num[0][hh] = fmaf(p0, axj[0][e], num[0][hh]);                  \
                den[1][hh] = fmaf(p1, am[1][e],  den[1][hh]);                  \
                num[1][hh] = fmaf(p1, axj[1][e], num[1][hh]);                  \
            }                                                                  \
        }                                                                      \
    } while (0)

// Main: 4 rows/block, 8 waves = (row-pair 0/1) x (h-group 0/1) x (j-half 0/1).
__global__ __launch_bounds__(512) void gat_main(const float* __restrict__ x,
                                                const int* __restrict__ adj,
                                                const float* __restrict__ W,
                                                float* __restrict__ out) {
    __shared__ float part[2][2][4][6][2];   // [jh][hg][rloc][hh][den,num]
    __shared__ float cbuf[4][GAT_H];

    const int tid   = threadIdx.x;
    const int row0  = blockIdx.x * 4;
    const int lane  = tid & 63;
    const int wave  = tid >> 6;          // 0..7
    const int rp    = wave >> 2;         // 0..1 row pair
    const int hg    = (wave >> 1) & 1;   // 0..1 head group
    const int jh    = wave & 1;          // 0..1 j half
    const int hbase = hg * 6;

    // rho (wave-uniform) -> SGPR-pinned
    float rho[2][6];
    #pragma unroll
    for (int r = 0; r < 2; ++r) {
        const float xr = x[row0 + rp * 2 + r];
        #pragma unroll
        for (int hh = 0; hh < 6; ++hh)
            rho[r][hh] = __uint_as_float(__builtin_amdgcn_readfirstlane(
                __float_as_uint(__builtin_amdgcn_exp2f(
                    -0.8f * LOG2E * xr * g_sd[hbase + hh]))));
    }

    float den[2][6], num[2][6];
    #pragma unroll
    for (int r = 0; r < 2; ++r)
        #pragma unroll
        for (int hh = 0; hh < 6; ++hh) { den[r][hh] = 0.0f; num[r][hh] = 0.0f; }

    // 4 j per lane: j = jh*2048 + it*256 + 4*lane + e
    const int4* __restrict__ a4p0 =
        (const int4*)(adj + (size_t)(row0 + rp * 2) * GAT_N + jh * 2048);
    const int4* __restrict__ a4p1 = a4p0 + (GAT_N / 4);
    const float4* __restrict__ t4 =
        (const float4*)(g_tab2 + hbase * GAT_N + jh * 2048);
    const float4* __restrict__ x4 = (const float4*)(x + jh * 2048);

    int4   aBuf[2][2];
    float4 tBuf[2][6];
    float4 xBuf[2];

    // Prologue: adj 2 deep; table/x 1 deep.
    aBuf[0][0] = a4p0[lane];      aBuf[0][1] = a4p1[lane];
    aBuf[1][0] = a4p0[64 + lane]; aBuf[1][1] = a4p1[64 + lane];
    #pragma unroll
    for (int hh = 0; hh < 6; ++hh) tBuf[0][hh] = t4[hh * (GAT_N / 4) + lane];
    xBuf[0] = x4[lane];

    for (int k = 0; k < 4; ++k) {
        GAT_ITER(0, 2 * k);
        GAT_ITER(1, 2 * k + 1);
    }

    // wave reduction -> partials
    #pragma unroll
    for (int r = 0; r < 2; ++r) {
        #pragma unroll
        for (int hh = 0; hh < 6; ++hh) {
            float d = den[r][hh], n = num[r][hh];
            #pragma unroll
            for (int off = 32; off > 0; off >>= 1) {
                d += __shfl_xor(d, off, 64);
                n += __shfl_xor(n, off, 64);
            }
            if (lane == 0) {
                part[jh][hg][rp * 2 + r][hh][0] = d;
                part[jh][hg][rp * 2 + r][hh][1] = n;
            }
        }
    }
    __syncthreads();

    if (tid < 64) {
        const int r = tid >> 4, h = tid & 15;
        if (h < GAT_H) {
            const int g  = (h >= 6) ? 1 : 0;
            const int hh = h - 6 * g;
            const float dsum = part[0][g][r][hh][0] + part[1][g][r][hh][0];
            const float nsum = part[0][g][r][hh][1] + part[1][g][r][hh][1];
            cbuf[r][h] = dsum > 0.0f ? nsum / dsum : g_sd[2 * GAT_H];
        }
    }
    __syncthreads();

    // Epilogue: out[row][h*64+f] = c[row][h] * W[h*64+f]; pos == h*64+f.
    #pragma unroll
    for (int rr = 0; rr < 4; ++rr) {
        const size_t base = (size_t)(row0 + rr) * (GAT_H * GAT_F);
        #pragma unroll
        for (int k = 0; k < 2; ++k) {
            const int pos = k * 512 + tid;
            if (pos < GAT_H * GAT_F)
                out[base + pos] = cbuf[rr][pos >> 6] * W[pos];
        }
    }
}

extern "C" void kernel_launch(void* const* d_in, const int* in_sizes, int n_in,
                              void* d_out, int out_size, void* d_ws, size_t ws_size,
                              hipStream_t stream) {
    const float* x   = (const float*)d_in[0];
    const int*   adj = (const int*)d_in[1];
    const float* W   = (const float*)d_in[2];
    const float* a   = (const float*)d_in[3];
    float* out = (float*)d_out;
    (void)d_ws; (void)ws_size;   // all scratch is static __device__ memory

    gat_prep<<<GAT_H + 1 + 48, 256, 0, stream>>>(W, a, x);
    gat_main<<<GAT_N / 4, 512, 0, stream>>>(x, adj, W, out);
}

// Round 9
// 128.816 us; speedup vs baseline: 1.1083x; 1.1083x over previous
//
#include <hip/hip_runtime.h>

#define GAT_H 12
#define GAT_N 4096
#define GAT_F 64
#define LOG2E 1.4426950408889634f

// ---------------------------------------------------------------------------
// Algebra: with q = x_i*s_h + x_j*d_h,
//   exp(lrelu(q)) = B1(i,h) * max(E2^4, rho(i,h)) * E2
//   where E2  = exp2(0.2*log2e*d_h*x_j)   [192 KB table, L2-resident]
//         rho = exp2(-0.8*log2e*x_i*s_h)  [SGPR-pinned]
// B1 cancels in softmax. Inner per (i,j,h): shared sq/sq + max+mul+2fma.
//
// R6 measured defect: adj (HBM ~900cyc) prefetched only 1 iter (~560cyc)
// ahead; per-iter barrier synced the stall into every wave (~460 idle
// cyc/iter). R7 showed register-resident table prefetch trips the allocator
// (AGPR shuttle). Round 8 = R6 + (a) adj/x prefetch DEPTH 2 (consumer
// distance ~1100cyc > HBM), issue-ordered so the ds_write wait leaves the
// pipe in flight; (b) 2 rows/wave, 8 rows/block: table reads, staging,
// barriers amortized over 2 rows; each (row,head) owned by one wave -> no
// cross-wave combine. ~85 live VGPRs (R5-proven allocator-safe).
// ---------------------------------------------------------------------------

__device__ float g_tab2[GAT_H * GAT_N];   // 192 KB: E2 table
__device__ float g_sd[2 * GAT_H + 1];     // s[12], d[12], mean(x)

__global__ __launch_bounds__(256) void gat_prep(const float* __restrict__ W,
                                                const float* __restrict__ a,
                                                const float* __restrict__ x) {
    const int b    = blockIdx.x;
    const int tid  = threadIdx.x;
    const int lane = tid & 63;
    const int wave = tid >> 6;

    if (b < GAT_H) {                       // s_h, d_h (wave 0 only)
        if (wave == 0) {
            const float wf = W[b * GAT_F + lane];
            float ps = wf * a[b * 2 * GAT_F + lane];
            float pd = wf * a[b * 2 * GAT_F + GAT_F + lane];
            #pragma unroll
            for (int off = 32; off > 0; off >>= 1) {
                ps += __shfl_xor(ps, off, 64);
                pd += __shfl_xor(pd, off, 64);
            }
            if (lane == 0) { g_sd[b] = ps; g_sd[GAT_H + b] = pd; }
        }
        return;
    }
    if (b == GAT_H) {                      // mean(x) fallback (wave 0 only)
        if (wave == 0) {
            float s = 0.0f;
            #pragma unroll
            for (int j = 0; j < GAT_N / 64; ++j) s += x[j * 64 + lane];
            #pragma unroll
            for (int off = 32; off > 0; off >>= 1) s += __shfl_xor(s, off, 64);
            if (lane == 0) g_sd[2 * GAT_H] = s * (1.0f / GAT_N);
        }
        return;
    }

    // Table blocks: bt in [0,48): h = bt>>2, 1024-wide j-chunk = bt&3.
    const int bt    = b - (GAT_H + 1);
    const int h     = bt >> 2;
    const int chunk = bt & 3;
    const float wf  = W[h * GAT_F + lane];
    float pd = wf * a[h * 2 * GAT_F + GAT_F + lane];
    #pragma unroll
    for (int off = 32; off > 0; off >>= 1) pd += __shfl_xor(pd, off, 64);
    const float dl5 = 0.2f * pd * LOG2E;
    #pragma unroll
    for (int k = 0; k < 4; ++k) {
        const int j = chunk * 1024 + k * 256 + tid;
        g_tab2[h * GAT_N + j] = __builtin_amdgcn_exp2f(dl5 * x[j]);
    }
}

// Main: 8 rows/block, 8 waves = row-pair(4) x head-group(2); 16 iters of 256 j.
__global__ __launch_bounds__(512) void gat_main(const float* __restrict__ x,
                                                const int* __restrict__ adj,
                                                const float* __restrict__ W,
                                                float* __restrict__ out) {
    __shared__ float tab_lds[2][GAT_H][256];   // 24 KB, double-buffered slice
    __shared__ float cbuf[8][GAT_H];

    const int tid   = threadIdx.x;
    const int row0  = blockIdx.x * 8;
    const int lane  = tid & 63;
    const int wave  = tid >> 6;          // 0..7
    const int rp    = wave >> 1;         // 0..3 row pair
    const int hg    = wave & 1;          // 0..1 head group
    const int hbase = hg * 6;
    const int rowA  = row0 + rp * 2;

    // rho (wave-uniform) -> SGPR-pinned
    float rho[2][6];
    #pragma unroll
    for (int r = 0; r < 2; ++r) {
        const float xr = x[rowA + r];
        #pragma unroll
        for (int hh = 0; hh < 6; ++hh)
            rho[r][hh] = __uint_as_float(__builtin_amdgcn_readfirstlane(
                __float_as_uint(__builtin_amdgcn_exp2f(
                    -0.8f * LOG2E * xr * g_sd[hbase + hh]))));
    }

    float den[2][6], num[2][6];
    #pragma unroll
    for (int r = 0; r < 2; ++r)
        #pragma unroll
        for (int hh = 0; hh < 6; ++hh) { den[r][hh] = 0.0f; num[r][hh] = 0.0f; }

    // Staging geometry: slice = [12 heads][256 j] = 1536 float2; 3/thread.
    const float2* __restrict__ tg = (const float2*)g_tab2;   // [h][2048] pairs
    int sh[3], sj[3];
    #pragma unroll
    for (int k = 0; k < 3; ++k) {
        const int p = k * 512 + tid;
        sh[k] = p >> 7;
        sj[k] = p & 127;
    }
    float2* __restrict__ lds2 = (float2*)tab_lds;            // [2][12][128] pairs

    // Prologue: stage slice 0 into buf 0; adj/x pipe 2 deep.
    #pragma unroll
    for (int k = 0; k < 3; ++k)
        lds2[sh[k] * 128 + sj[k]] = tg[sh[k] * (GAT_N / 2) + sj[k]];
    const int4*   __restrict__ a4p0 = (const int4*)(adj + (size_t)rowA * GAT_N);
    const int4*   __restrict__ a4p1 = a4p0 + (GAT_N / 4);
    const float4* __restrict__ x4   = (const float4*)x;

    int4   aP0[2], aP1[2];
    float4 xP[2];
    aP0[0] = a4p0[lane];      aP1[0] = a4p1[lane];      xP[0] = x4[lane];
    aP0[1] = a4p0[64 + lane]; aP1[1] = a4p1[64 + lane]; xP[1] = x4[64 + lane];
    __syncthreads();

    #pragma unroll 2
    for (int it = 0; it < 16; ++it) {
        const int buf = it & 1;                 // literal under unroll-2

        // 1) consume pipe slot (vmcnt waits only for the 2-iter-old loads)
        float am[2][4], axj[2][4];
        {
            const int*   ai0 = (const int*)&aP0[buf];
            const int*   ai1 = (const int*)&aP1[buf];
            const float* xp  = (const float*)&xP[buf];
            #pragma unroll
            for (int e = 0; e < 4; ++e) {
                am[0][e]  = (float)ai0[e];
                am[1][e]  = (float)ai1[e];
                axj[0][e] = am[0][e] * xp[e];
                axj[1][e] = am[1][e] * xp[e];
            }
        }

        // 2) issue next-slice staging loads (it+1)
        const int n1 = (it < 15) ? it + 1 : 15;
        float2 st[3];
        #pragma unroll
        for (int k = 0; k < 3; ++k)
            st[k] = tg[sh[k] * (GAT_N / 2) + n1 * 128 + sj[k]];

        // 3) refill pipe slot with it+2 (consumed two iterations from now)
        const int n2i = ((it < 14) ? it + 2 : 15) * 64 + lane;
        aP0[buf] = a4p0[n2i];
        aP1[buf] = a4p1[n2i];
        xP[buf]  = x4[n2i];

        // 4) compute from staged slice (conflict-free ds_read_b128)
        #pragma unroll
        for (int hh = 0; hh < 6; ++hh) {
            const float4 e2v = *(const float4*)&tab_lds[buf][hbase + hh][4 * lane];
            const float* e2  = (const float*)&e2v;
            #pragma unroll
            for (int e = 0; e < 4; ++e) {
                const float w  = e2[e] * e2[e];
                const float w4 = w * w;                          // E2^4
                const float p0 = fmaxf(w4, rho[0][hh]) * e2[e];  // max(E1,rho*E2)
                const float p1 = fmaxf(w4, rho[1][hh]) * e2[e];
                den[0][hh] = fmaf(p0, am[0][e],  den[0][hh]);
                num[0][hh] = fmaf(p0, axj[0][e], num[0][hh]);
                den[1][hh] = fmaf(p1, am[1][e],  den[1][hh]);
                num[1][hh] = fmaf(p1, axj[1][e], num[1][hh]);
            }
        }

        // 5) write next slice (wait = vmcnt(3): adj/x pipe stays in flight)
        #pragma unroll
        for (int k = 0; k < 3; ++k)
            lds2[(buf ^ 1) * (GAT_H * 128) + sh[k] * 128 + sj[k]] = st[k];
        __syncthreads();
    }

    // Each (row, head) owned by exactly one wave: reduce and write directly.
    #pragma unroll
    for (int r = 0; r < 2; ++r) {
        #pragma unroll
        for (int hh = 0; hh < 6; ++hh) {
            float d = den[r][hh], n = num[r][hh];
            #pragma unroll
            for (int off = 32; off > 0; off >>= 1) {
                d += __shfl_xor(d, off, 64);
                n += __shfl_xor(n, off, 64);
            }
            if (lane == 0)
                cbuf[rp * 2 + r][hbase + hh] =
                    d > 0.0f ? n / d : g_sd[2 * GAT_H];
        }
    }
    __syncthreads();

    // Epilogue: out[row][h*64+f] = c[row][h] * W[h*64+f]; pos == h*64+f.
    #pragma unroll
    for (int rr = 0; rr < 8; ++rr) {
        const size_t base = (size_t)(row0 + rr) * (GAT_H * GAT_F);
        #pragma unroll
        for (int k = 0; k < 2; ++k) {
            const int pos = k * 512 + tid;
            if (pos < GAT_H * GAT_F)
                out[base + pos] = cbuf[rr][pos >> 6] * W[pos];
        }
    }
}

extern "C" void kernel_launch(void* const* d_in, const int* in_sizes, int n_in,
                              void* d_out, int out_size, void* d_ws, size_t ws_size,
                              hipStream_t stream) {
    const float* x   = (const float*)d_in[0];
    const int*   adj = (const int*)d_in[1];
    const float* W   = (const float*)d_in[2];
    const float* a   = (const float*)d_in[3];
    float* out = (float*)d_out;
    (void)d_ws; (void)ws_size;   // all scratch is static __device__ memory

    gat_prep<<<GAT_H + 1 + 48, 256, 0, stream>>>(W, a, x);
    gat_main<<<GAT_N / 8, 512, 0, stream>>>(x, adj, W, out);
}